// Round 13
// baseline (364.427 us; speedup 1.0000x reference)
//
#include <hip/hip_runtime.h>
#include <hip/hip_bf16.h>
#include <math.h>

#define H_HEADS 4
#define D_HEAD 512
#define HD 2048
#define IN_DIM 256
#define OUTD 512
#define NEG 0.2f

typedef __hip_bfloat16 bf16;
typedef _Float16 f16;
typedef __attribute__((ext_vector_type(2))) _Float16 h2v;  // packed fp16 pair
typedef __attribute__((ext_vector_type(8))) short s16x8;   // 8 x bf16 (4 VGPRs)
typedef __attribute__((ext_vector_type(4))) float f32x4;   // MFMA accumulator

__device__ __forceinline__ float bflo(unsigned w) { union { unsigned u; float f; } x; x.u = w << 16; return x.f; }
__device__ __forceinline__ float bfhi(unsigned w) { union { unsigned u; float f; } x; x.u = w & 0xffff0000u; return x.f; }

// ---------------- batched MFMA bf16 GEMM body ----------------
// C_z[row, col] = sum_k A_z[row, k] * Bt_z[col, k]
// MODE 0: bf16 output, + bias[col].
// MODE 1: fp32 output, fused: lrelu(acc + bias[col] + (deg(row)>0 ? bias2[col] : 0)).
// MODE 2: f16 output, + bias[col].
// Tile 128x128, BK=32; staging rows clamped to M-1 (never stored OOB).
// K-loop: 2-phase double-buffer, stage issued AFTER the barrier (r4 lesson).
// 16-bit epilogue: single-phase, one barrier, 8 coalesced store iters.
template<int MODE>
__device__ __forceinline__ void gemm_body(char* smem_raw,
                      const bf16* __restrict__ A, int lda, long aOff,
                      const bf16* __restrict__ Bt, int ldb, long bOff,
                      const float* __restrict__ bias, long biasOff,
                      const float* __restrict__ bias2, const int* __restrict__ rowptr,
                      void* __restrict__ Cv, int ldc, long cOff,
                      int M, int K, int bx, int by, int z)
{
    bf16* stg = (bf16*)smem_raw;   // [2][A:4096 | B:4096] elements

    const int tid  = threadIdx.x;
    const int r0   = by * 128;
    const int n0   = bx * 128;
    const int lane = tid & 63;
    const int wave = tid >> 6;
    const int wr   = (wave >> 1) * 64;
    const int wc   = (wave & 1) * 64;
    const int l15  = lane & 15;
    const int quad = lane >> 4;

    const bf16* Az = A + aOff * (long)z;
    const bf16* Bz = Bt + bOff * (long)z;

    f32x4 acc[4][4];
    #pragma unroll
    for (int i = 0; i < 4; i++)
        #pragma unroll
        for (int j = 0; j < 4; j++)
            #pragma unroll
            for (int r = 0; r < 4; r++) acc[i][j][r] = 0.f;

    const int srow = tid >> 2;
    // XOR-swizzle: this lane fetches global chunk (k8 ^ key(row)); same 64B window.
    const int skof = (((tid & 3) ^ ((srow >> 1) & 3)) * 8);
    const int swz  = (l15 >> 1) & 3;   // reader-side key: row&15 == l15

    auto stage_tile = [&](int c, int k0) {
        bf16* As = stg + c * 8192;
        bf16* Bs = As + 4096;
        #pragma unroll
        for (int p = 0; p < 2; p++) {
            int ar = r0 + p * 64 + srow;
            if (ar >= M) ar = M - 1;
            const bf16* ga = Az + (size_t)ar * lda + k0 + skof;
            __builtin_amdgcn_global_load_lds(
                (const __attribute__((address_space(1))) void*)ga,
                (__attribute__((address_space(3))) void*)(As + (p * 256 + tid) * 8),
                16, 0, 0);
            const bf16* gb = Bz + (size_t)(n0 + p * 64 + srow) * ldb + k0 + skof;
            __builtin_amdgcn_global_load_lds(
                (const __attribute__((address_space(1))) void*)gb,
                (__attribute__((address_space(3))) void*)(Bs + (p * 256 + tid) * 8),
                16, 0, 0);
        }
    };

    stage_tile(0, 0);              // prologue prefetch (drained by first barrier)
    int cbuf = 0;
    for (int k0 = 0; k0 < K; k0 += 32) {
        __syncthreads();           // drains tile-k0 loads (one iteration old)
        if (k0 + 32 < K) stage_tile(cbuf ^ 1, k0 + 32);   // prefetch AFTER barrier

        const bf16* As = stg + cbuf * 8192;
        const bf16* Bs = As + 4096;
        s16x8 af[4], bg[4];
        #pragma unroll
        for (int i = 0; i < 4; i++)
            af[i] = *(const s16x8*)(As + (wr + i * 16 + l15) * 32 + (quad ^ swz) * 8);
        #pragma unroll
        for (int j = 0; j < 4; j++)
            bg[j] = *(const s16x8*)(Bs + (wc + j * 16 + l15) * 32 + (quad ^ swz) * 8);
        #pragma unroll
        for (int i = 0; i < 4; i++)
            #pragma unroll
            for (int j = 0; j < 4; j++)
                acc[i][j] = __builtin_amdgcn_mfma_f32_16x16x32_bf16(af[i], bg[j], acc[i][j], 0, 0, 0);
        cbuf ^= 1;
    }
    __syncthreads();               // all waves done reading stg before epilogue reuse

    // C/D frag layout: col = lane&15, row = quad*4 + reg (m89/m91 verified)
    if (MODE == 0 || MODE == 2) {
        float bv[4];
        #pragma unroll
        for (int j = 0; j < 4; j++)
            bv[j] = bias ? bias[biasOff * (long)z + n0 + wc + j * 16 + l15] : 0.f;

        const long cb = cOff * (long)z;

        // single-phase transpose: every wave writes its own quadrant
        if (MODE == 0) {
            bf16* Cs = (bf16*)smem_raw;
            #pragma unroll
            for (int i = 0; i < 4; i++)
                #pragma unroll
                for (int j = 0; j < 4; j++)
                    #pragma unroll
                    for (int r = 0; r < 4; r++)
                        Cs[(wr + i * 16 + quad * 4 + r) * 136 + wc + j * 16 + l15] =
                            __float2bfloat16(acc[i][j][r] + bv[j]);
        } else {
            f16* Cs = (f16*)smem_raw;
            #pragma unroll
            for (int i = 0; i < 4; i++)
                #pragma unroll
                for (int j = 0; j < 4; j++)
                    #pragma unroll
                    for (int r = 0; r < 4; r++)
                        Cs[(wr + i * 16 + quad * 4 + r) * 136 + wc + j * 16 + l15] =
                            (f16)(acc[i][j][r] + bv[j]);
        }
        __syncthreads();
        #pragma unroll
        for (int it = 0; it < 8; it++) {
            const int idx  = it * 256 + tid;
            const int lrow = idx >> 4;
            const int lcol = (idx & 15) * 8;
            const int grow = r0 + lrow;
            if (grow < M)
                *(uint4*)((short*)Cv + cb + (size_t)grow * ldc + n0 + lcol) =
                    *(const uint4*)((const short*)smem_raw + lrow * 136 + lcol);
        }
    } else {
        float* C = (float*)Cv;
        float* Csf = (float*)smem_raw;     // 64 x 132 (padded)

        #pragma unroll
        for (int p = 0; p < 2; p++) {
            __syncthreads();
            if (wr == p * 64) {
                #pragma unroll
                for (int i = 0; i < 4; i++)
                    #pragma unroll
                    for (int j = 0; j < 4; j++)
                        #pragma unroll
                        for (int r = 0; r < 4; r++)
                            Csf[(i * 16 + quad * 4 + r) * 132 + wc + j * 16 + l15] = acc[i][j][r];
            }
            __syncthreads();
            #pragma unroll
            for (int it = 0; it < 8; it++) {
                const int idx  = it * 256 + tid;
                const int lrow = idx >> 5;
                const int lcol = (idx & 31) * 4;
                const int grow = r0 + p * 64 + lrow;
                if (grow < M) {
                    const int gcol = n0 + lcol;
                    float4 v  = *(const float4*)(Csf + lrow * 132 + lcol);
                    const float4 c4 = *(const float4*)(bias + gcol);
                    const float4 b4 = *(const float4*)(bias2 + gcol);
                    const bool has = rowptr[grow + 1] > rowptr[grow];
                    v.x += c4.x + (has ? b4.x : 0.f);
                    v.y += c4.y + (has ? b4.y : 0.f);
                    v.z += c4.z + (has ? b4.z : 0.f);
                    v.w += c4.w + (has ? b4.w : 0.f);
                    v.x = v.x > 0.f ? v.x : NEG * v.x;
                    v.y = v.y > 0.f ? v.y : NEG * v.y;
                    v.z = v.z > 0.f ? v.z : NEG * v.z;
                    v.w = v.w > 0.f ? v.w : NEG * v.w;
                    *(float4*)(C + (size_t)grow * ldc + gcol) = v;
                }
            }
        }
    }
}

// Bijective chunked XCD swizzle (m204): consecutive logical blocks (which
// share A-panels) land on ONE XCD's L2. Perf-only permutation (round-9: -10us).
__device__ __forceinline__ int xcd_swizzle_flat()
{
    const int nwg = gridDim.x * gridDim.y * gridDim.z;
    int f = blockIdx.x + gridDim.x * (blockIdx.y + gridDim.y * blockIdx.z);
    const int xcd = f & 7;
    const int i   = f >> 3;
    const int q = nwg >> 3, r = nwg & 7;
    return (xcd < r ? xcd * (q + 1) : r * (q + 1) + (xcd - r) * q) + i;
}

// Standalone wrapper (used for MODE 1 / the out-GEMM).
template<int MODE>
__global__ __launch_bounds__(256)
void mfma_gemm_kernel(const bf16* __restrict__ A, int lda, long aOff,
                      const bf16* __restrict__ Bt, int ldb, long bOff,
                      const float* __restrict__ bias, long biasOff,
                      const float* __restrict__ bias2, const int* __restrict__ rowptr,
                      void* __restrict__ Cv, int ldc, long cOff,
                      int M, int K)
{
    constexpr int SMEM_BYTES = (MODE == 1) ? (64 * 132 * 4) : (128 * 136 * 2);
    static_assert(SMEM_BYTES >= 4 * 4096 * 2, "staging dbuf must fit");
    __shared__ __align__(16) char smem_raw[SMEM_BYTES];
    const int f   = xcd_swizzle_flat();
    const int bx  = f % gridDim.x;
    const int byz = f / gridDim.x;
    gemm_body<MODE>(smem_raw, A, lda, aOff, Bt, ldb, bOff, bias, biasOff,
                    bias2, rowptr, Cv, ldc, cOff, M, K,
                    bx, byz % gridDim.y, byz / gridDim.y);
}

// FUSED launch: 1-D grid of EXACTLY 32+nMain blocks (r11: no dead blocks).
// The 32 Wfinal (MODE-0, K=512) blocks are logical IDs [0,32) — FRONT of
// XCD-0's chunk, earliest dispatch — so their 2x-deep K-loop overlaps the
// 5024-block main GEMM instead of trailing it (r12). One shared LDS buffer.
__global__ __launch_bounds__(256)
void fused_gemm02_kernel(int gx, int gy, int nMain,
    const bf16* __restrict__ A2, int lda2, long aOff2,
    const bf16* __restrict__ B2, int ldb2, long bOff2,
    const float* __restrict__ bias2v, long biasOff2,
    void* __restrict__ C2, int ldc2, long cOff2, int M2, int K2,
    const bf16* __restrict__ A0, int lda0, long aOff0,
    const bf16* __restrict__ B0, int ldb0, long bOff0,
    void* __restrict__ C0, int ldc0, long cOff0, int M0, int K0)
{
    __shared__ __align__(16) char smem_raw[128 * 136 * 2];
    const int f = xcd_swizzle_flat();
    if (f < 32) {
        const int bx0 = f & 1;             // 2 x 4 x 4 Wfinal blocks
        const int by0 = (f >> 1) & 3;
        const int z0  = f >> 3;
        gemm_body<0>(smem_raw, A0, lda0, aOff0, B0, ldb0, bOff0, nullptr, 0,
                     nullptr, nullptr, C0, ldc0, cOff0, M0, K0, bx0, by0, z0);
    } else {
        const int fm = f - 32;
        const int bx = fm % gx;
        const int t  = fm / gx;
        gemm_body<2>(smem_raw, A2, lda2, aOff2, B2, ldb2, bOff2, bias2v, biasOff2,
                     nullptr, nullptr, C2, ldc2, cOff2, M2, K2, bx, t % gy, t / gy);
    }
}

// ---------------- prep: transposes + casts (incl. z) + misc + reductions ----------------
// Round-6: 32x32 LDS-tiled transposes (coalesced both sides, [32][33] pad).
// Round-13: z-cast folded in (was its own launch); misc zeroes cnt + lookback
// flags + the 2 grid-barrier counters for csr_build (re-poison safe).
__global__ __launch_bounds__(256)
void prep_kernel(const float* __restrict__ W_src, const float* __restrict__ W_dst,
                 const float* __restrict__ W_fc, const float* __restrict__ b_src,
                 const float* __restrict__ b_dst, const float* __restrict__ attn,
                 const float* __restrict__ b_fc, const float* __restrict__ gat_bias,
                 const float* __restrict__ zsrc, bf16* __restrict__ zb, long nzb,
                 bf16* __restrict__ WsbT, bf16* __restrict__ WdbT,
                 bf16* __restrict__ WfcT, bf16* __restrict__ Wsb,
                 float* __restrict__ bias_cat, f16* __restrict__ atn16,
                 int* __restrict__ cnt, int nCnt,
                 float* __restrict__ cvec, float* __restrict__ bsW_tot,
                 int zcastB, int miscB)
{
    __shared__ float tile[32][33];
    const int b   = blockIdx.x;
    const int tid = threadIdx.x;
    const int tx  = tid & 31;
    const int ty0 = tid >> 5;          // 0..7

    if (b < 1024) {
        // 256x2048 -> 2048x256 transpose (A: W_src->WsbT, B: W_dst->WdbT)
        const float* In = (b < 512) ? W_src : W_dst;
        bf16* Out       = (b < 512) ? WsbT : WdbT;
        const int a  = b & 511;
        const int bk = a & 7;           // k-tile (8 tiles over 256)
        const int bn = a >> 3;          // n-tile (64 tiles over 2048)
        #pragma unroll
        for (int i = 0; i < 4; i++) {
            const int r = ty0 + i * 8;
            tile[r][tx] = In[(size_t)(bk * 32 + r) * HD + bn * 32 + tx];
        }
        __syncthreads();
        #pragma unroll
        for (int i = 0; i < 4; i++) {
            const int r = ty0 + i * 8;
            Out[(size_t)(bn * 32 + r) * IN_DIM + bk * 32 + tx] = __float2bfloat16(tile[tx][r]);
        }
        return;
    }
    if (b < 2048) {
        // per-head 512x512 transpose: WfcT[(h*512+j)*512+t] = W_fc[(h*512+t)*512+j]
        const int c  = b - 1024;
        const int h  = c >> 8;
        const int r8 = c & 255;
        const int bt = r8 & 15;
        const int bj = r8 >> 4;
        #pragma unroll
        for (int i = 0; i < 4; i++) {
            const int r = ty0 + i * 8;
            tile[r][tx] = W_fc[(size_t)(h * 512 + bt * 32 + r) * OUTD + bj * 32 + tx];
        }
        __syncthreads();
        #pragma unroll
        for (int i = 0; i < 4; i++) {
            const int r = ty0 + i * 8;
            WfcT[(size_t)(h * 512 + bj * 32 + r) * 512 + bt * 32 + tx] = __float2bfloat16(tile[tx][r]);
        }
        return;
    }
    if (b < 2560) {
        // Wsb: straight cast, float4 loads
        const int i4 = ((b - 2048) * 256 + tid) * 4;
        const float4 v = *(const float4*)(W_src + i4);
        Wsb[i4 + 0] = __float2bfloat16(v.x);
        Wsb[i4 + 1] = __float2bfloat16(v.y);
        Wsb[i4 + 2] = __float2bfloat16(v.z);
        Wsb[i4 + 3] = __float2bfloat16(v.w);
        return;
    }
    if (b < 2560 + zcastB) {
        // z cast (folded from the old cast_hist launch)
        const long i = ((long)(b - 2560) * 256 + tid) * 4;
        if (i < nzb) {
            const float4 v = *(const float4*)(zsrc + i);
            zb[i + 0] = __float2bfloat16(v.x);
            zb[i + 1] = __float2bfloat16(v.y);
            zb[i + 2] = __float2bfloat16(v.z);
            zb[i + 3] = __float2bfloat16(v.w);
        }
        return;
    }
    if (b < 2560 + zcastB + miscB) {
        int idx = (b - 2560 - zcastB) * 256 + tid;
        if (idx < 2 * HD) { bias_cat[idx] = (idx < HD) ? b_src[idx] : b_dst[idx - HD]; return; }
        idx -= 2 * HD;
        if (idx < HD) { atn16[idx] = (f16)attn[idx]; return; }
        idx -= HD;
        if (idx < nCnt) cnt[idx] = 0;   // cnt[N] + flags[128] + sync[2]
        return;
    }
    // reduction role: cvec[j] = gat_bias @ W_fc[:,j] + b_fc[j]  (first OUTD blocks)
    //                 bsW_tot[j] = b_src @ W_fc[:,j]            (next OUTD blocks)
    {
        __shared__ float red[256];
        const int rb = b - (2560 + zcastB + miscB);
        const bool isCvec = rb < OUTD;
        const int j = isCvec ? rb : rb - OUTD;
        const float* vec = isCvec ? gat_bias : b_src;
        float s = 0.f;
        for (int k = tid; k < HD; k += 256)
            s = fmaf(vec[k], W_fc[(size_t)k * OUTD + j], s);
        red[tid] = s;
        __syncthreads();
        for (int o = 128; o > 0; o >>= 1) {
            if (tid < o) red[tid] += red[tid + o];
            __syncthreads();
        }
        if (tid == 0) {
            if (isCvec) cvec[j] = red[0] + b_fc[j];
            else bsW_tot[j] = red[0];
        }
    }
}

// ---------------- fused CSR build: hist + scan + scatter in ONE launch ----------------
// Round-13: replaces 3 launches (cast_hist's hist tail, scan, scatter) ->
// saves 2 launch gaps (~14us each). Hand-rolled grid barriers are SAFE here:
// nb = 391 blocks x 256 thr, trivially co-resident on 256 CUs (capacity 2048
// blocks), so every block reaches the barrier -> no deadlock.
// Cross-XCD visibility: phase-1 writes cnt via device-scope atomics; phase-2
// READS cnt via atomicAdd(,0) and WRITES cursor via atomicExch (device-scope),
// so phase-3's atomicAdd on cursor sees finalized values. rowptr/csr_src are
// only read by LATER KERNELS (kernel boundary flushes). sync/flags/cnt all
// zeroed by prep each iteration.
__global__ __launch_bounds__(256)
void csr_build_kernel(const int* __restrict__ src, const int* __restrict__ dst,
                      int* __restrict__ cnt, int* __restrict__ rowptr,
                      int* __restrict__ cursor, int* __restrict__ csr_src,
                      int* __restrict__ flags, int* __restrict__ syncv,
                      int N, int E, int nb, int nScan)
{
    const int tid  = threadIdx.x;
    const int lane = tid & 63;
    const int wv   = tid >> 6;
    const int b    = blockIdx.x;

    // phase 1: degree histogram
    for (int e = b * 256 + tid; e < E; e += nb * 256)
        atomicAdd(&cnt[dst[e]], 1);
    __syncthreads();
    if (tid == 0) {
        __threadfence();
        atomicAdd(&syncv[0], 1);
        while (atomicAdd(&syncv[0], 0) < nb) { }
    }
    __syncthreads();

    // phase 2: lookback scan over cnt (blocks < nScan)
    if (b < nScan) {
        __shared__ int ws[4];
        __shared__ int exoff_s;
        const int i = b * 256 + tid;
        int v = (i < N) ? atomicAdd(&cnt[i], 0) : 0;   // coherent read
        #pragma unroll
        for (int d = 1; d < 64; d <<= 1) {
            const int t = __shfl_up(v, d, 64);
            if (lane >= d) v += t;
        }
        if (lane == 63) ws[wv] = v;
        __syncthreads();
        int s = 0;
        if (wv > 0) s += ws[0];
        if (wv > 1) s += ws[1];
        if (wv > 2) s += ws[2];
        const int incl = v + s;
        if (tid == 255)
            atomicExch(&flags[b], incl + 1);           // publish total (+1 = ready)
        if (wv == 0) {
            int acc = 0;
            for (int idx = lane; idx < b; idx += 64) {
                int r;
                do { r = atomicAdd(&flags[idx], 0); } while (r == 0);
                acc += r - 1;
            }
            #pragma unroll
            for (int ofs = 32; ofs > 0; ofs >>= 1)
                acc += __shfl_xor(acc, ofs, 64);
            if (lane == 0) exoff_s = acc;
        }
        __syncthreads();
        const int r = incl + exoff_s;
        if (i < N) {
            rowptr[i + 1] = r;                         // read by later kernels only
            if (i + 1 < N) atomicExch(&cursor[i + 1], r);   // read by phase 3
        }
        if (b == 0 && tid == 0) { rowptr[0] = 0; atomicExch(&cursor[0], 0); }
    }
    __syncthreads();
    if (tid == 0) {
        __threadfence();
        atomicAdd(&syncv[1], 1);
        while (atomicAdd(&syncv[1], 0) < nb) { }
    }
    __syncthreads();

    // phase 3: scatter edges into CSR
    for (int e = b * 256 + tid; e < E; e += nb * 256) {
        const int pos = atomicAdd(&cursor[dst[e]], 1);
        csr_src[pos] = src[e];
    }
}

// ---------------- edge scores: packed-f16 math ----------------
// LeakyReLU(s, 0.2) == 0.6*s + 0.4*|s|, branch-free; |s| via sign-bit mask on
// the packed word. All ops compile to v_pk_{add,mul,fma}_f16.
__device__ __forceinline__ _Float16 score_head_pk(const uint4 pa, const uint4 pb, const uint4 at)
{
    const unsigned* ua = (const unsigned*)&pa;
    const unsigned* ub = (const unsigned*)&pb;
    const unsigned* ut = (const unsigned*)&at;
    h2v acc = (h2v)(_Float16)0.f;
    const h2v c06 = (h2v)(_Float16)0.6f;
    const h2v c04 = (h2v)(_Float16)0.4f;
    #pragma unroll
    for (int c = 0; c < 4; c++) {
        union { unsigned u; h2v h; } A, B, T, S, Ab;
        A.u = ua[c]; B.u = ub[c]; T.u = ut[c];
        S.h = A.h + B.h;
        Ab.u = S.u & 0x7fff7fffu;
        const h2v l = S.h * c06 + Ab.h * c04;
        acc += l * T.h;
    }
    return acc.x + acc.y;
}

__device__ __forceinline__ float score_head_h2(const uint4 pa, const uint4 pb, const uint4 at)
{
    const unsigned* ua = (const unsigned*)&pa;
    const unsigned* ub = (const unsigned*)&pb;
    const unsigned* ut = (const unsigned*)&at;
    h2v acc = (h2v)(_Float16)0.f;
    const h2v c06 = (h2v)(_Float16)0.6f;
    const h2v c04 = (h2v)(_Float16)0.4f;
    #pragma unroll
    for (int c = 0; c < 4; c++) {
        union { unsigned u; h2v h; } A, B, T, S, Ab;
        A.u = ua[c]; B.u = ub[c]; T.u = ut[c];
        S.h = A.h + B.h;
        Ab.u = S.u & 0x7fff7fffu;
        const h2v l = S.h * c06 + Ab.h * c04;
        acc += l * T.h;
    }
    return (float)acc.x + (float)acc.y;
}

// ---------------- FUSED score + z-space aggregation, per-(node,head) ----------------
// block = node, wave = head. 4-EDGE UNROLL (round-5: 8-edge blew VGPR/occupancy).
// f16-packed score reduction (round-8: neutral on time, kept — fewer ops, same
// accuracy). Tail edges index-clamped (dup gather, L1-hit) with zeroed weights.
// agg[v, h*256+k] = (sum_e exp(s_eh) * zb[u_e, k]) / (sum_e exp(s_eh))
__global__ __launch_bounds__(256)
void score_agg_kernel(const f16* __restrict__ fs, const f16* __restrict__ fd,
                      const bf16* __restrict__ zb,
                      const int* __restrict__ rowptr, const int* __restrict__ csr_src,
                      const f16* __restrict__ atn16, bf16* __restrict__ agg, int N)
{
    const int h    = threadIdx.x >> 6;     // wave index = head
    const int lane = threadIdx.x & 63;
    const int v    = blockIdx.x;
    if (v >= N) return;

    const uint4 at = *(const uint4*)(atn16 + h * D_HEAD + lane * 8);
    const f16* fsh = fs + h * D_HEAD + (size_t)lane * 8;

    const int off0 = rowptr[v], off1 = rowptr[v + 1];
    const int deg  = off1 - off0;
    float acc[4] = {0.f, 0.f, 0.f, 0.f};
    float den = 0.f;

    const uint4 fdr = *(const uint4*)(fd + (size_t)v * HD + h * D_HEAD + lane * 8);

    for (int e = 0; e < deg; e += 4) {
        const int i0 = off0 + e;
        const int i1 = off0 + ((e + 1 < deg) ? e + 1 : e);
        const int i2 = off0 + ((e + 2 < deg) ? e + 2 : e);
        const int i3 = off0 + ((e + 3 < deg) ? e + 3 : e);
        const int u0 = csr_src[i0], u1 = csr_src[i1], u2 = csr_src[i2], u3 = csr_src[i3];

        const uint4 pa0 = *(const uint4*)(fsh + (size_t)u0 * HD);
        const uint4 pa1 = *(const uint4*)(fsh + (size_t)u1 * HD);
        const uint4 pa2 = *(const uint4*)(fsh + (size_t)u2 * HD);
        const uint4 pa3 = *(const uint4*)(fsh + (size_t)u3 * HD);
        const uint2 z0 = *(const uint2*)(zb + (size_t)u0 * IN_DIM + lane * 4);
        const uint2 z1 = *(const uint2*)(zb + (size_t)u1 * IN_DIM + lane * 4);
        const uint2 z2 = *(const uint2*)(zb + (size_t)u2 * IN_DIM + lane * 4);
        const uint2 z3 = *(const uint2*)(zb + (size_t)u3 * IN_DIM + lane * 4);

        // two packed words: (edge0, edge1) and (edge2, edge3)
        union { unsigned u; h2v h; } w01, w23;
        w01.h.x = score_head_pk(pa0, fdr, at);
        w01.h.y = score_head_pk(pa1, fdr, at);
        w23.h.x = score_head_pk(pa2, fdr, at);
        w23.h.y = score_head_pk(pa3, fdr, at);
        #pragma unroll
        for (int ofs = 32; ofs > 0; ofs >>= 1) {
            union { int i; h2v h; } t01, t23;
            t01.i = __shfl_xor((int)w01.u, ofs, 64);
            t23.i = __shfl_xor((int)w23.u, ofs, 64);
            w01.h += t01.h;           // v_pk_add_f16
            w23.h += t23.h;
        }
        const float s0 = (float)w01.h.x;
        const float s1 = (float)w01.h.y;
        const float s2 = (float)w23.h.x;
        const float s3 = (float)w23.h.y;
        // scores O(0.2): max-subtraction safely skipped (cancels in num/den
        // anyway, so deferred normalization is exact)
        const float e0 = __expf(s0);
        const float e1 = (e + 1 < deg) ? __expf(s1) : 0.f;
        const float e2 = (e + 2 < deg) ? __expf(s2) : 0.f;
        const float e3 = (e + 3 < deg) ? __expf(s3) : 0.f;
        den += e0 + e1 + e2 + e3;
        const float zc0[4] = {bflo(z0.x), bfhi(z0.x), bflo(z0.y), bfhi(z0.y)};
        const float zc1[4] = {bflo(z1.x), bfhi(z1.x), bflo(z1.y), bfhi(z1.y)};
        const float zc2[4] = {bflo(z2.x), bfhi(z2.x), bflo(z2.y), bfhi(z2.y)};
        const float zc3[4] = {bflo(z3.x), bfhi(z3.x), bflo(z3.y), bfhi(z3.y)};
        #pragma unroll
        for (int c = 0; c < 4; c++)
            acc[c] += (e0 * zc0[c] + e1 * zc1[c]) + (e2 * zc2[c] + e3 * zc3[c]);
    }
    if (deg > 0) {
        const float inv = 1.f / den;
        #pragma unroll
        for (int c = 0; c < 4; c++) acc[c] *= inv;
    }

    union { uint2 u; short s[4]; } pk;
    #pragma unroll
    for (int c = 0; c < 4; c++) {
        const bf16 b = __float2bfloat16(acc[c]);
        pk.s[c] = *(const short*)&b;
    }
    *(uint2*)(agg + (size_t)v * (H_HEADS * IN_DIM) + h * IN_DIM + lane * 4) = pk.u;
}

// ---------------- fallback pair (used only if workspace too small for a
// separate agg buffer; agg then overlays fs, so score/agg must be 2 passes)
__global__ __launch_bounds__(256)
void score_csr_kernel(const f16* __restrict__ fs, const f16* __restrict__ fd,
                      const int* __restrict__ rowptr, const int* __restrict__ csr_src,
                      const f16* __restrict__ atn16, float* __restrict__ expbuf,
                      float* __restrict__ denomB, int N)
{
    const int wave = threadIdx.x >> 6;
    const int lane = threadIdx.x & 63;
    const int wgid = blockIdx.x * 4 + wave;
    const int nw   = gridDim.x * 4;

    uint4 at[H_HEADS];
    #pragma unroll
    for (int h = 0; h < H_HEADS; h++)
        at[h] = *(const uint4*)(atn16 + h * D_HEAD + lane * 8);

    for (int v = wgid; v < N; v += nw) {
        const int off0 = rowptr[v], off1 = rowptr[v + 1];
        if (off0 == off1) continue;
        uint4 fdr[H_HEADS];
        #pragma unroll
        for (int h = 0; h < H_HEADS; h++)
            fdr[h] = *(const uint4*)(fd + (size_t)v * HD + h * D_HEAD + lane * 8);

        float4 den = make_float4(0.f, 0.f, 0.f, 0.f);
        for (int o = off0; o < off1; o += 2) {
            const bool two = (o + 1 < off1);
            const int u0 = csr_src[o];
            const int u1 = two ? csr_src[o + 1] : u0;
            const f16* f0 = fs + (size_t)u0 * HD + lane * 8;
            const f16* f1 = fs + (size_t)u1 * HD + lane * 8;
            uint4 pa0[H_HEADS], pa1[H_HEADS];
            #pragma unroll
            for (int h = 0; h < H_HEADS; h++) pa0[h] = *(const uint4*)(f0 + h * D_HEAD);
            #pragma unroll
            for (int h = 0; h < H_HEADS; h++) pa1[h] = *(const uint4*)(f1 + h * D_HEAD);

            float s0[H_HEADS], s1[H_HEADS];
            #pragma unroll
            for (int h = 0; h < H_HEADS; h++) {
                s0[h] = score_head_h2(pa0[h], fdr[h], at[h]);
                s1[h] = score_head_h2(pa1[h], fdr[h], at[h]);
            }
            #pragma unroll
            for (int ofs = 32; ofs > 0; ofs >>= 1) {
                #pragma unroll
                for (int h = 0; h < H_HEADS; h++) {
                    s0[h] += __shfl_xor(s0[h], ofs, 64);
                    s1[h] += __shfl_xor(s1[h], ofs, 64);
                }
            }
            const float4 e0 = make_float4(expf(s0[0]), expf(s0[1]), expf(s0[2]), expf(s0[3]));
            den.x += e0.x; den.y += e0.y; den.z += e0.z; den.w += e0.w;
            float4 e1;
            if (two) {
                e1 = make_float4(expf(s1[0]), expf(s1[1]), expf(s1[2]), expf(s1[3]));
                den.x += e1.x; den.y += e1.y; den.z += e1.z; den.w += e1.w;
            }
            if (lane == 0) {
                *(float4*)(expbuf + (size_t)o * H_HEADS) = e0;
                if (two) *(float4*)(expbuf + (size_t)(o + 1) * H_HEADS) = e1;
            }
        }
        if (lane == 0) *(float4*)(denomB + (size_t)v * H_HEADS) = den;
    }
}

__global__ __launch_bounds__(256)
void agg_z_kernel(const bf16* __restrict__ zb, const int* __restrict__ rowptr,
                  const int* __restrict__ csr_src, const float* __restrict__ expbuf,
                  const float* __restrict__ denomB, bf16* __restrict__ agg, int N)
{
    const int wave = threadIdx.x >> 6;
    const int lane = threadIdx.x & 63;
    const int wgid = blockIdx.x * 4 + wave;
    const int nw   = gridDim.x * 4;

    for (int v = wgid; v < N; v += nw) {
        const int off0 = rowptr[v], off1 = rowptr[v + 1];
        float acc[H_HEADS][4];
        #pragma unroll
        for (int h = 0; h < H_HEADS; h++)
            #pragma unroll
            for (int c = 0; c < 4; c++) acc[h][c] = 0.f;

        if (off1 > off0) {
            const float4 den = *(const float4*)(denomB + (size_t)v * H_HEADS);
            const float4 inv = make_float4(1.f / den.x, 1.f / den.y, 1.f / den.z, 1.f / den.w);
            int o = off0;
            for (; o + 1 < off1; o += 2) {
                const float4 e0 = *(const float4*)(expbuf + (size_t)o * H_HEADS);
                const float4 e1 = *(const float4*)(expbuf + (size_t)(o + 1) * H_HEADS);
                const int u0 = csr_src[o], u1 = csr_src[o + 1];
                const uint2 z0 = *(const uint2*)(zb + (size_t)u0 * IN_DIM + lane * 4);
                const uint2 z1 = *(const uint2*)(zb + (size_t)u1 * IN_DIM + lane * 4);
                const float a0[4] = {e0.x * inv.x, e0.y * inv.y, e0.z * inv.z, e0.w * inv.w};
                const float a1[4] = {e1.x * inv.x, e1.y * inv.y, e1.z * inv.z, e1.w * inv.w};
                const float zc0[4] = {bflo(z0.x), bfhi(z0.x), bflo(z0.y), bfhi(z0.y)};
                const float zc1[4] = {bflo(z1.x), bfhi(z1.x), bflo(z1.y), bfhi(z1.y)};
                #pragma unroll
                for (int h = 0; h < H_HEADS; h++)
                    #pragma unroll
                    for (int c = 0; c < 4; c++)
                        acc[h][c] += a0[h] * zc0[c] + a1[h] * zc1[c];
            }
            if (o < off1) {
                const float4 e0 = *(const float4*)(expbuf + (size_t)o * H_HEADS);
                const int u0 = csr_src[o];
                const uint2 z0 = *(const uint2*)(zb + (size_t)u0 * IN_DIM + lane * 4);
                const float a0[4] = {e0.x * inv.x, e0.y * inv.y, e0.z * inv.z, e0.w * inv.w};
                const float zc0[4] = {bflo(z0.x), bfhi(z0.x), bflo(z0.y), bfhi(z0.y)};
                #pragma unroll
                for (int h = 0; h < H_HEADS; h++)
                    #pragma unroll
                    for (int c = 0; c < 4; c++)
                        acc[h][c] += a0[h] * zc0[c];
            }
        }
        #pragma unroll
        for (int h = 0; h < H_HEADS; h++) {
            union { uint2 u; short s[4]; } pk;
            #pragma unroll
            for (int c = 0; c < 4; c++) {
                const bf16 b = __float2bfloat16(acc[h][c]);
                pk.s[c] = *(const short*)&b;
            }
            *(uint2*)(agg + (size_t)v * (H_HEADS * IN_DIM) + h * IN_DIM + lane * 4) = pk.u;
        }
    }
}

extern "C" void kernel_launch(void* const* d_in, const int* in_sizes, int n_in,
                              void* d_out, int out_size, void* d_ws, size_t ws_size,
                              hipStream_t stream)
{
    const float* z        = (const float*)d_in[0];
    const int*   src      = (const int*)d_in[1];
    const int*   dst      = (const int*)d_in[2];
    const float* W_src    = (const float*)d_in[3];
    const float* b_src    = (const float*)d_in[4];
    const float* W_dst    = (const float*)d_in[5];
    const float* b_dst    = (const float*)d_in[6];
    const float* attn     = (const float*)d_in[7];
    const float* gat_bias = (const float*)d_in[8];
    const float* W_fc     = (const float*)d_in[9];
    const float* b_fc     = (const float*)d_in[10];
    float* out = (float*)d_out;

    const int N = in_sizes[0] / IN_DIM;   // 20000
    const int E = in_sizes[1];            // 100000
    const int nScan  = (N + 255) / 256;   // 79
    const int nEdgeB = (E + 255) / 256;   // 391

    // Workspace (~184 MB base; +41 MB for separate agg if ws_size allows).
    char* p = (char*)d_ws;
    const size_t featB = (size_t)N * HD * 2;
    f16* fs       = (f16*)p;   p += featB;                               // 81.92 MB (f16)
    f16* fd       = (f16*)p;   p += featB;                               // 81.92 MB (f16)
    bf16* zb      = (bf16*)p;  p += (size_t)N * IN_DIM * sizeof(bf16);   // 10.24 MB
    bf16* WsbT    = (bf16*)p;  p += (size_t)HD * IN_DIM * sizeof(bf16);  // 1.05 MB
    bf16* WdbT    = (bf16*)p;  p += (size_t)HD * IN_DIM * sizeof(bf16);  // 1.05 MB
    bf16* Wsb     = (bf16*)p;  p += (size_t)IN_DIM * HD * sizeof(bf16);  // 1.05 MB
    bf16* WfcT    = (bf16*)p;  p += (size_t)HD * D_HEAD * sizeof(bf16);  // 2.10 MB
    bf16* Wfinal  = (bf16*)p;  p += (size_t)OUTD * 1024 * sizeof(bf16);  // 1.05 MB
    float* bias_cat = (float*)p; p += (size_t)2 * HD * sizeof(float);    // 16 KB
    f16* atn16    = (f16*)p;   p += (size_t)HD * sizeof(f16);            // 4 KB
    float* bsW_tot = (float*)p; p += (size_t)OUTD * sizeof(float);
    float* cvec   = (float*)p; p += (size_t)OUTD * sizeof(float);
    float* expbuf = (float*)p; p += (size_t)E * H_HEADS * sizeof(float); // 1.6 MB
    float* denomB = (float*)p; p += (size_t)N * H_HEADS * sizeof(float); // 0.32 MB
    int* cnt      = (int*)p;   p += (size_t)N * 4;                       // N ints
    int* flags    = (int*)p;   p += (size_t)128 * 4;                     // lookback flags
    int* syncv    = (int*)p;   p += (size_t)2 * 4;                       // grid barriers
    p = (char*)(((size_t)p + 15) & ~15ULL);
    int* rowptr   = (int*)p;   p += ((size_t)(N + 1) * 4 + 15) & ~15ULL;
    int* cursor   = (int*)p;   p += ((size_t)N * 4 + 15) & ~15ULL;
    int* csr_src  = (int*)p;   p += ((size_t)E * 4 + 15) & ~15ULL;

    // Separate agg buffer (fused score+agg needs fs live while writing agg);
    // fall back to overlaying fs + 2-pass kernels if workspace is too small.
    bf16* aggSep = (bf16*)p;
    const size_t needFused = (size_t)(p - (char*)d_ws) + (size_t)N * (H_HEADS * IN_DIM) * sizeof(bf16);
    const bool fused = (ws_size >= needFused);
    bf16* agg = fused ? aggSep : (bf16*)fs;

    // Prep: transposes + casts (incl. z) + misc (cnt/flags/sync zero) + reductions.
    const long nzb = (long)N * IN_DIM;
    const int zcastB = (int)((nzb / 4 + 255) / 256);          // 5000
    const int miscElems = 2 * HD + HD + (N + 128 + 2);
    const int miscB = (miscElems + 255) / 256;
    prep_kernel<<<2560 + zcastB + miscB + 2 * OUTD, 256, 0, stream>>>(
        W_src, W_dst, W_fc, b_src, b_dst, attn, b_fc, gat_bias,
        z, zb, nzb,
        WsbT, WdbT, WfcT, Wsb, bias_cat, atn16, cnt, N + 128 + 2,
        cvec, bsW_tot, zcastB, miscB);

    // CSR build: hist + scan + scatter in one launch (hand grid barriers).
    csr_build_kernel<<<nEdgeB, 256, 0, stream>>>(
        src, dst, cnt, rowptr, cursor, csr_src, flags, syncv, N, E, nEdgeB, nScan);

    // FUSED: logical [0,32) = Wfinal GEMM (front -> overlaps), [32,32+nMain) =
    // fs/fd GEMM.
    //   fs,fd = zb @ {W_src,W_dst} + {b_src,b_dst} (f16 out)
    //   Wfinal[j, h*256+k] = Wcomb_h[k, j]         (bf16 out)
    const int gx = HD / 128;                  // 16
    const int gy = (N + 127) / 128;           // 157
    const int nMain = gx * gy * 2;            // 5024
    fused_gemm02_kernel<<<nMain + 32, 256, 0, stream>>>(
        gx, gy, nMain,
        zb, IN_DIM, 0L,
        WsbT, IN_DIM, (long)HD * IN_DIM,
        bias_cat, (long)HD,
        fs, HD, (long)N * HD,
        N, IN_DIM,
        WfcT, D_HEAD, (long)D_HEAD * D_HEAD,
        Wsb, HD, (long)D_HEAD,
        Wfinal, 1024, (long)IN_DIM,
        D_HEAD, D_HEAD);

    // Edge scores + z-space aggregation
    if (fused) {
        score_agg_kernel<<<N, 256, 0, stream>>>(fs, fd, zb, rowptr, csr_src, atn16, agg, N);
    } else {
        score_csr_kernel<<<2500, 256, 0, stream>>>(fs, fd, rowptr, csr_src, atn16, expbuf, denomB, N);
        agg_z_kernel<<<2500, 256, 0, stream>>>(zb, rowptr, csr_src, expbuf, denomB, agg, N);
    }

    // out = lrelu(agg @ Wfinal^T + cvec + deg?bsW_tot), fused epilogue
    mfma_gemm_kernel<1><<<dim3(OUTD / 128, (N + 127) / 128, 1), 256, 0, stream>>>(
        agg, H_HEADS * IN_DIM, 0L,
        Wfinal, H_HEADS * IN_DIM, 0L,
        cvec, 0L, bsW_tot, rowptr,
        out, OUTD, 0L,
        N, H_HEADS * IN_DIM);
}

// Round 14
// 308.420 us; speedup vs baseline: 1.1816x; 1.1816x over previous
//
#include <hip/hip_runtime.h>
#include <hip/hip_bf16.h>
#include <math.h>

#define H_HEADS 4
#define D_HEAD 512
#define HD 2048
#define IN_DIM 256
#define OUTD 512
#define NEG 0.2f

typedef __hip_bfloat16 bf16;
typedef _Float16 f16;
typedef __attribute__((ext_vector_type(2))) _Float16 h2v;  // packed fp16 pair
typedef __attribute__((ext_vector_type(8))) short s16x8;   // 8 x bf16 (4 VGPRs)
typedef __attribute__((ext_vector_type(4))) float f32x4;   // MFMA accumulator

__device__ __forceinline__ float bflo(unsigned w) { union { unsigned u; float f; } x; x.u = w << 16; return x.f; }
__device__ __forceinline__ float bfhi(unsigned w) { union { unsigned u; float f; } x; x.u = w & 0xffff0000u; return x.f; }

// ---------------- batched MFMA bf16 GEMM body ----------------
// C_z[row, col] = sum_k A_z[row, k] * Bt_z[col, k]
// MODE 0: bf16 output, + bias[col].
// MODE 1: fp32 output, fused: lrelu(acc + bias[col] + (deg(row)>0 ? bias2[col] : 0)).
// MODE 2: f16 output, + bias[col].
// Tile 128x128, BK=32; staging rows clamped to M-1 (never stored OOB).
// K-loop: 2-phase double-buffer, stage issued AFTER the barrier (r4 lesson).
// 16-bit epilogue: single-phase, one barrier, 8 coalesced store iters.
// (r13 lesson: device-side grid-barrier fusion of the CSR chain cost -52us —
// spin-polling one cacheline from 391 blocks across 8 non-coherent L2s is far
// worse than a kernel boundary. This file is the r12 best-known config.)
template<int MODE>
__device__ __forceinline__ void gemm_body(char* smem_raw,
                      const bf16* __restrict__ A, int lda, long aOff,
                      const bf16* __restrict__ Bt, int ldb, long bOff,
                      const float* __restrict__ bias, long biasOff,
                      const float* __restrict__ bias2, const int* __restrict__ rowptr,
                      void* __restrict__ Cv, int ldc, long cOff,
                      int M, int K, int bx, int by, int z)
{
    bf16* stg = (bf16*)smem_raw;   // [2][A:4096 | B:4096] elements

    const int tid  = threadIdx.x;
    const int r0   = by * 128;
    const int n0   = bx * 128;
    const int lane = tid & 63;
    const int wave = tid >> 6;
    const int wr   = (wave >> 1) * 64;
    const int wc   = (wave & 1) * 64;
    const int l15  = lane & 15;
    const int quad = lane >> 4;

    const bf16* Az = A + aOff * (long)z;
    const bf16* Bz = Bt + bOff * (long)z;

    f32x4 acc[4][4];
    #pragma unroll
    for (int i = 0; i < 4; i++)
        #pragma unroll
        for (int j = 0; j < 4; j++)
            #pragma unroll
            for (int r = 0; r < 4; r++) acc[i][j][r] = 0.f;

    const int srow = tid >> 2;
    // XOR-swizzle: this lane fetches global chunk (k8 ^ key(row)); same 64B window.
    const int skof = (((tid & 3) ^ ((srow >> 1) & 3)) * 8);
    const int swz  = (l15 >> 1) & 3;   // reader-side key: row&15 == l15

    auto stage_tile = [&](int c, int k0) {
        bf16* As = stg + c * 8192;
        bf16* Bs = As + 4096;
        #pragma unroll
        for (int p = 0; p < 2; p++) {
            int ar = r0 + p * 64 + srow;
            if (ar >= M) ar = M - 1;
            const bf16* ga = Az + (size_t)ar * lda + k0 + skof;
            __builtin_amdgcn_global_load_lds(
                (const __attribute__((address_space(1))) void*)ga,
                (__attribute__((address_space(3))) void*)(As + (p * 256 + tid) * 8),
                16, 0, 0);
            const bf16* gb = Bz + (size_t)(n0 + p * 64 + srow) * ldb + k0 + skof;
            __builtin_amdgcn_global_load_lds(
                (const __attribute__((address_space(1))) void*)gb,
                (__attribute__((address_space(3))) void*)(Bs + (p * 256 + tid) * 8),
                16, 0, 0);
        }
    };

    stage_tile(0, 0);              // prologue prefetch (drained by first barrier)
    int cbuf = 0;
    for (int k0 = 0; k0 < K; k0 += 32) {
        __syncthreads();           // drains tile-k0 loads (one iteration old)
        if (k0 + 32 < K) stage_tile(cbuf ^ 1, k0 + 32);   // prefetch AFTER barrier

        const bf16* As = stg + cbuf * 8192;
        const bf16* Bs = As + 4096;
        s16x8 af[4], bg[4];
        #pragma unroll
        for (int i = 0; i < 4; i++)
            af[i] = *(const s16x8*)(As + (wr + i * 16 + l15) * 32 + (quad ^ swz) * 8);
        #pragma unroll
        for (int j = 0; j < 4; j++)
            bg[j] = *(const s16x8*)(Bs + (wc + j * 16 + l15) * 32 + (quad ^ swz) * 8);
        #pragma unroll
        for (int i = 0; i < 4; i++)
            #pragma unroll
            for (int j = 0; j < 4; j++)
                acc[i][j] = __builtin_amdgcn_mfma_f32_16x16x32_bf16(af[i], bg[j], acc[i][j], 0, 0, 0);
        cbuf ^= 1;
    }
    __syncthreads();               // all waves done reading stg before epilogue reuse

    // C/D frag layout: col = lane&15, row = quad*4 + reg (m89/m91 verified)
    if (MODE == 0 || MODE == 2) {
        float bv[4];
        #pragma unroll
        for (int j = 0; j < 4; j++)
            bv[j] = bias ? bias[biasOff * (long)z + n0 + wc + j * 16 + l15] : 0.f;

        const long cb = cOff * (long)z;

        // single-phase transpose: every wave writes its own quadrant
        if (MODE == 0) {
            bf16* Cs = (bf16*)smem_raw;
            #pragma unroll
            for (int i = 0; i < 4; i++)
                #pragma unroll
                for (int j = 0; j < 4; j++)
                    #pragma unroll
                    for (int r = 0; r < 4; r++)
                        Cs[(wr + i * 16 + quad * 4 + r) * 136 + wc + j * 16 + l15] =
                            __float2bfloat16(acc[i][j][r] + bv[j]);
        } else {
            f16* Cs = (f16*)smem_raw;
            #pragma unroll
            for (int i = 0; i < 4; i++)
                #pragma unroll
                for (int j = 0; j < 4; j++)
                    #pragma unroll
                    for (int r = 0; r < 4; r++)
                        Cs[(wr + i * 16 + quad * 4 + r) * 136 + wc + j * 16 + l15] =
                            (f16)(acc[i][j][r] + bv[j]);
        }
        __syncthreads();
        #pragma unroll
        for (int it = 0; it < 8; it++) {
            const int idx  = it * 256 + tid;
            const int lrow = idx >> 4;
            const int lcol = (idx & 15) * 8;
            const int grow = r0 + lrow;
            if (grow < M)
                *(uint4*)((short*)Cv + cb + (size_t)grow * ldc + n0 + lcol) =
                    *(const uint4*)((const short*)smem_raw + lrow * 136 + lcol);
        }
    } else {
        float* C = (float*)Cv;
        float* Csf = (float*)smem_raw;     // 64 x 132 (padded)

        #pragma unroll
        for (int p = 0; p < 2; p++) {
            __syncthreads();
            if (wr == p * 64) {
                #pragma unroll
                for (int i = 0; i < 4; i++)
                    #pragma unroll
                    for (int j = 0; j < 4; j++)
                        #pragma unroll
                        for (int r = 0; r < 4; r++)
                            Csf[(i * 16 + quad * 4 + r) * 132 + wc + j * 16 + l15] = acc[i][j][r];
            }
            __syncthreads();
            #pragma unroll
            for (int it = 0; it < 8; it++) {
                const int idx  = it * 256 + tid;
                const int lrow = idx >> 5;
                const int lcol = (idx & 31) * 4;
                const int grow = r0 + p * 64 + lrow;
                if (grow < M) {
                    const int gcol = n0 + lcol;
                    float4 v  = *(const float4*)(Csf + lrow * 132 + lcol);
                    const float4 c4 = *(const float4*)(bias + gcol);
                    const float4 b4 = *(const float4*)(bias2 + gcol);
                    const bool has = rowptr[grow + 1] > rowptr[grow];
                    v.x += c4.x + (has ? b4.x : 0.f);
                    v.y += c4.y + (has ? b4.y : 0.f);
                    v.z += c4.z + (has ? b4.z : 0.f);
                    v.w += c4.w + (has ? b4.w : 0.f);
                    v.x = v.x > 0.f ? v.x : NEG * v.x;
                    v.y = v.y > 0.f ? v.y : NEG * v.y;
                    v.z = v.z > 0.f ? v.z : NEG * v.z;
                    v.w = v.w > 0.f ? v.w : NEG * v.w;
                    *(float4*)(C + (size_t)grow * ldc + gcol) = v;
                }
            }
        }
    }
}

// Bijective chunked XCD swizzle (m204): consecutive logical blocks (which
// share A-panels) land on ONE XCD's L2. Perf-only permutation (round-9: -10us).
__device__ __forceinline__ int xcd_swizzle_flat()
{
    const int nwg = gridDim.x * gridDim.y * gridDim.z;
    int f = blockIdx.x + gridDim.x * (blockIdx.y + gridDim.y * blockIdx.z);
    const int xcd = f & 7;
    const int i   = f >> 3;
    const int q = nwg >> 3, r = nwg & 7;
    return (xcd < r ? xcd * (q + 1) : r * (q + 1) + (xcd - r) * q) + i;
}

// Standalone wrapper (used for MODE 1 / the out-GEMM).
template<int MODE>
__global__ __launch_bounds__(256)
void mfma_gemm_kernel(const bf16* __restrict__ A, int lda, long aOff,
                      const bf16* __restrict__ Bt, int ldb, long bOff,
                      const float* __restrict__ bias, long biasOff,
                      const float* __restrict__ bias2, const int* __restrict__ rowptr,
                      void* __restrict__ Cv, int ldc, long cOff,
                      int M, int K)
{
    constexpr int SMEM_BYTES = (MODE == 1) ? (64 * 132 * 4) : (128 * 136 * 2);
    static_assert(SMEM_BYTES >= 4 * 4096 * 2, "staging dbuf must fit");
    __shared__ __align__(16) char smem_raw[SMEM_BYTES];
    const int f   = xcd_swizzle_flat();
    const int bx  = f % gridDim.x;
    const int byz = f / gridDim.x;
    gemm_body<MODE>(smem_raw, A, lda, aOff, Bt, ldb, bOff, bias, biasOff,
                    bias2, rowptr, Cv, ldc, cOff, M, K,
                    bx, byz % gridDim.y, byz / gridDim.y);
}

// FUSED launch: 1-D grid of EXACTLY 32+nMain blocks (r11: no dead blocks).
// The 32 Wfinal (MODE-0, K=512) blocks are logical IDs [0,32) — FRONT of
// XCD-0's chunk, earliest dispatch — so their 2x-deep K-loop overlaps the
// 5024-block main GEMM instead of trailing it (r12). One shared LDS buffer.
__global__ __launch_bounds__(256)
void fused_gemm02_kernel(int gx, int gy, int nMain,
    const bf16* __restrict__ A2, int lda2, long aOff2,
    const bf16* __restrict__ B2, int ldb2, long bOff2,
    const float* __restrict__ bias2v, long biasOff2,
    void* __restrict__ C2, int ldc2, long cOff2, int M2, int K2,
    const bf16* __restrict__ A0, int lda0, long aOff0,
    const bf16* __restrict__ B0, int ldb0, long bOff0,
    void* __restrict__ C0, int ldc0, long cOff0, int M0, int K0)
{
    __shared__ __align__(16) char smem_raw[128 * 136 * 2];
    const int f = xcd_swizzle_flat();
    if (f < 32) {
        const int bx0 = f & 1;             // 2 x 4 x 4 Wfinal blocks
        const int by0 = (f >> 1) & 3;
        const int z0  = f >> 3;
        gemm_body<0>(smem_raw, A0, lda0, aOff0, B0, ldb0, bOff0, nullptr, 0,
                     nullptr, nullptr, C0, ldc0, cOff0, M0, K0, bx0, by0, z0);
    } else {
        const int fm = f - 32;
        const int bx = fm % gx;
        const int t  = fm / gx;
        gemm_body<2>(smem_raw, A2, lda2, aOff2, B2, ldb2, bOff2, bias2v, biasOff2,
                     nullptr, nullptr, C2, ldc2, cOff2, M2, K2, bx, t % gy, t / gy);
    }
}

// ---------------- prep: LDS-tiled transposes + casts + misc + reductions ----------------
// Round-6 lesson: per-element transposes read with 2-8KB stride (~8-16x
// over-fetch). 32x32 LDS tiles: coalesced read, padded [32][33], coalesced write.
// misc role also zeroes the scan lookback flags (nCnt = N + 128).
__global__ __launch_bounds__(256)
void prep_kernel(const float* __restrict__ W_src, const float* __restrict__ W_dst,
                 const float* __restrict__ W_fc, const float* __restrict__ b_src,
                 const float* __restrict__ b_dst, const float* __restrict__ attn,
                 const float* __restrict__ b_fc, const float* __restrict__ gat_bias,
                 bf16* __restrict__ WsbT, bf16* __restrict__ WdbT,
                 bf16* __restrict__ WfcT, bf16* __restrict__ Wsb,
                 float* __restrict__ bias_cat, f16* __restrict__ atn16,
                 int* __restrict__ cnt, int nCnt,
                 float* __restrict__ cvec, float* __restrict__ bsW_tot, int miscB)
{
    __shared__ float tile[32][33];
    const int b   = blockIdx.x;
    const int tid = threadIdx.x;
    const int tx  = tid & 31;
    const int ty0 = tid >> 5;          // 0..7

    if (b < 1024) {
        // 256x2048 -> 2048x256 transpose (A: W_src->WsbT, B: W_dst->WdbT)
        const float* In = (b < 512) ? W_src : W_dst;
        bf16* Out       = (b < 512) ? WsbT : WdbT;
        const int a  = b & 511;
        const int bk = a & 7;           // k-tile (8 tiles over 256)
        const int bn = a >> 3;          // n-tile (64 tiles over 2048)
        #pragma unroll
        for (int i = 0; i < 4; i++) {
            const int r = ty0 + i * 8;
            tile[r][tx] = In[(size_t)(bk * 32 + r) * HD + bn * 32 + tx];
        }
        __syncthreads();
        #pragma unroll
        for (int i = 0; i < 4; i++) {
            const int r = ty0 + i * 8;
            Out[(size_t)(bn * 32 + r) * IN_DIM + bk * 32 + tx] = __float2bfloat16(tile[tx][r]);
        }
        return;
    }
    if (b < 2048) {
        // per-head 512x512 transpose: WfcT[(h*512+j)*512+t] = W_fc[(h*512+t)*512+j]
        const int c  = b - 1024;
        const int h  = c >> 8;
        const int r8 = c & 255;
        const int bt = r8 & 15;
        const int bj = r8 >> 4;
        #pragma unroll
        for (int i = 0; i < 4; i++) {
            const int r = ty0 + i * 8;
            tile[r][tx] = W_fc[(size_t)(h * 512 + bt * 32 + r) * OUTD + bj * 32 + tx];
        }
        __syncthreads();
        #pragma unroll
        for (int i = 0; i < 4; i++) {
            const int r = ty0 + i * 8;
            WfcT[(size_t)(h * 512 + bj * 32 + r) * 512 + bt * 32 + tx] = __float2bfloat16(tile[tx][r]);
        }
        return;
    }
    if (b < 2560) {
        // Wsb: straight cast, float4 loads
        const int i4 = ((b - 2048) * 256 + tid) * 4;
        const float4 v = *(const float4*)(W_src + i4);
        Wsb[i4 + 0] = __float2bfloat16(v.x);
        Wsb[i4 + 1] = __float2bfloat16(v.y);
        Wsb[i4 + 2] = __float2bfloat16(v.z);
        Wsb[i4 + 3] = __float2bfloat16(v.w);
        return;
    }
    if (b < 2560 + miscB) {
        int idx = (b - 2560) * 256 + tid;
        if (idx < 2 * HD) { bias_cat[idx] = (idx < HD) ? b_src[idx] : b_dst[idx - HD]; return; }
        idx -= 2 * HD;
        if (idx < HD) { atn16[idx] = (f16)attn[idx]; return; }
        idx -= HD;
        if (idx < nCnt) cnt[idx] = 0;   // cnt[N] + lookback flags[128]
        return;
    }
    // reduction role: cvec[j] = gat_bias @ W_fc[:,j] + b_fc[j]  (first OUTD blocks)
    //                 bsW_tot[j] = b_src @ W_fc[:,j]            (next OUTD blocks)
    {
        __shared__ float red[256];
        const int rb = b - (2560 + miscB);
        const bool isCvec = rb < OUTD;
        const int j = isCvec ? rb : rb - OUTD;
        const float* vec = isCvec ? gat_bias : b_src;
        float s = 0.f;
        for (int k = tid; k < HD; k += 256)
            s = fmaf(vec[k], W_fc[(size_t)k * OUTD + j], s);
        red[tid] = s;
        __syncthreads();
        for (int o = 128; o > 0; o >>= 1) {
            if (tid < o) red[tid] += red[tid + o];
            __syncthreads();
        }
        if (tid == 0) {
            if (isCvec) cvec[j] = red[0] + b_fc[j];
            else bsW_tot[j] = red[0];
        }
    }
}

// cast z -> bf16, plus (tail range) degree histogram (cnt zeroed by prep)
__global__ void cast_hist_kernel(const float* __restrict__ S, bf16* __restrict__ T,
                                 long n4, const int* __restrict__ dst,
                                 int* __restrict__ cnt, int E)
{
    long t = (long)blockIdx.x * 256 + threadIdx.x;
    if (t < n4) {
        const long i = t * 4;
        const float4 v = *(const float4*)(S + i);
        T[i + 0] = __float2bfloat16(v.x);
        T[i + 1] = __float2bfloat16(v.y);
        T[i + 2] = __float2bfloat16(v.z);
        T[i + 3] = __float2bfloat16(v.w);
        return;
    }
    t -= n4;
    if (t < E) atomicAdd(&cnt[dst[t]], 1);
}

// ---------------- single-pass decoupled-lookback scan ----------------
// Each block: intra-block shfl scan, publish total via flags[b] = total+1
// (readiness + value in ONE atomic word -> no fence ordering needed), then one
// wave spin-sums the <=78 predecessor flags. All nb<=128 blocks are
// co-resident on 256 CUs, so every block sets its flag before spinning ->
// no deadlock. flags zeroed by prep.
__global__ __launch_bounds__(256)
void scan_lookback_kernel(const int* __restrict__ cnt, int* __restrict__ rowptr,
                          int* __restrict__ cursor, int* __restrict__ flags, int n)
{
    __shared__ int ws[4];
    __shared__ int exoff_s;
    const int tid  = threadIdx.x;
    const int lane = tid & 63;
    const int wv   = tid >> 6;
    const int b    = blockIdx.x;
    const int i    = b * 256 + tid;
    int v = (i < n) ? cnt[i] : 0;
    #pragma unroll
    for (int d = 1; d < 64; d <<= 1) {
        const int t = __shfl_up(v, d, 64);
        if (lane >= d) v += t;
    }
    if (lane == 63) ws[wv] = v;
    __syncthreads();
    int s = 0;
    if (wv > 0) s += ws[0];
    if (wv > 1) s += ws[1];
    if (wv > 2) s += ws[2];
    const int incl = v + s;                       // block-local inclusive
    if (tid == 255)
        atomicExch(&flags[b], incl + 1);          // publish total (+1 = ready)
    // wave 0: exclusive prefix over predecessor blocks
    if (wv == 0) {
        int acc = 0;
        for (int idx = lane; idx < b; idx += 64) {
            int r;
            do { r = atomicAdd(&flags[idx], 0); } while (r == 0);
            acc += r - 1;
        }
        #pragma unroll
        for (int ofs = 32; ofs > 0; ofs >>= 1)
            acc += __shfl_xor(acc, ofs, 64);
        if (lane == 0) exoff_s = acc;
    }
    __syncthreads();
    const int r = incl + exoff_s;
    if (i < n) {
        rowptr[i + 1] = r;
        if (i + 1 < n) cursor[i + 1] = r;
    }
    if (b == 0 && tid == 0) { rowptr[0] = 0; cursor[0] = 0; }
}

__global__ void scatter_kernel(const int* __restrict__ src, const int* __restrict__ dst,
                               int* __restrict__ cursor, int* __restrict__ csr_src, int E)
{
    const int e = blockIdx.x * 256 + threadIdx.x;
    if (e >= E) return;
    const int pos = atomicAdd(&cursor[dst[e]], 1);
    csr_src[pos] = src[e];
}

// ---------------- edge scores: packed-f16 math ----------------
// LeakyReLU(s, 0.2) == 0.6*s + 0.4*|s|, branch-free; |s| via sign-bit mask on
// the packed word. All ops compile to v_pk_{add,mul,fma}_f16.
__device__ __forceinline__ _Float16 score_head_pk(const uint4 pa, const uint4 pb, const uint4 at)
{
    const unsigned* ua = (const unsigned*)&pa;
    const unsigned* ub = (const unsigned*)&pb;
    const unsigned* ut = (const unsigned*)&at;
    h2v acc = (h2v)(_Float16)0.f;
    const h2v c06 = (h2v)(_Float16)0.6f;
    const h2v c04 = (h2v)(_Float16)0.4f;
    #pragma unroll
    for (int c = 0; c < 4; c++) {
        union { unsigned u; h2v h; } A, B, T, S, Ab;
        A.u = ua[c]; B.u = ub[c]; T.u = ut[c];
        S.h = A.h + B.h;
        Ab.u = S.u & 0x7fff7fffu;
        const h2v l = S.h * c06 + Ab.h * c04;
        acc += l * T.h;
    }
    return acc.x + acc.y;
}

__device__ __forceinline__ float score_head_h2(const uint4 pa, const uint4 pb, const uint4 at)
{
    const unsigned* ua = (const unsigned*)&pa;
    const unsigned* ub = (const unsigned*)&pb;
    const unsigned* ut = (const unsigned*)&at;
    h2v acc = (h2v)(_Float16)0.f;
    const h2v c06 = (h2v)(_Float16)0.6f;
    const h2v c04 = (h2v)(_Float16)0.4f;
    #pragma unroll
    for (int c = 0; c < 4; c++) {
        union { unsigned u; h2v h; } A, B, T, S, Ab;
        A.u = ua[c]; B.u = ub[c]; T.u = ut[c];
        S.h = A.h + B.h;
        Ab.u = S.u & 0x7fff7fffu;
        const h2v l = S.h * c06 + Ab.h * c04;
        acc += l * T.h;
    }
    return (float)acc.x + (float)acc.y;
}

// ---------------- FUSED score + z-space aggregation, per-(node,head) ----------------
// block = node, wave = head. 4-EDGE UNROLL (round-5: 8-edge blew VGPR/occupancy).
// f16-packed score reduction (round-8: neutral on time, kept — fewer ops, same
// accuracy). Tail edges index-clamped (dup gather, L1-hit) with zeroed weights.
// agg[v, h*256+k] = (sum_e exp(s_eh) * zb[u_e, k]) / (sum_e exp(s_eh))
__global__ __launch_bounds__(256)
void score_agg_kernel(const f16* __restrict__ fs, const f16* __restrict__ fd,
                      const bf16* __restrict__ zb,
                      const int* __restrict__ rowptr, const int* __restrict__ csr_src,
                      const f16* __restrict__ atn16, bf16* __restrict__ agg, int N)
{
    const int h    = threadIdx.x >> 6;     // wave index = head
    const int lane = threadIdx.x & 63;
    const int v    = blockIdx.x;
    if (v >= N) return;

    const uint4 at = *(const uint4*)(atn16 + h * D_HEAD + lane * 8);
    const f16* fsh = fs + h * D_HEAD + (size_t)lane * 8;

    const int off0 = rowptr[v], off1 = rowptr[v + 1];
    const int deg  = off1 - off0;
    float acc[4] = {0.f, 0.f, 0.f, 0.f};
    float den = 0.f;

    const uint4 fdr = *(const uint4*)(fd + (size_t)v * HD + h * D_HEAD + lane * 8);

    for (int e = 0; e < deg; e += 4) {
        const int i0 = off0 + e;
        const int i1 = off0 + ((e + 1 < deg) ? e + 1 : e);
        const int i2 = off0 + ((e + 2 < deg) ? e + 2 : e);
        const int i3 = off0 + ((e + 3 < deg) ? e + 3 : e);
        const int u0 = csr_src[i0], u1 = csr_src[i1], u2 = csr_src[i2], u3 = csr_src[i3];

        const uint4 pa0 = *(const uint4*)(fsh + (size_t)u0 * HD);
        const uint4 pa1 = *(const uint4*)(fsh + (size_t)u1 * HD);
        const uint4 pa2 = *(const uint4*)(fsh + (size_t)u2 * HD);
        const uint4 pa3 = *(const uint4*)(fsh + (size_t)u3 * HD);
        const uint2 z0 = *(const uint2*)(zb + (size_t)u0 * IN_DIM + lane * 4);
        const uint2 z1 = *(const uint2*)(zb + (size_t)u1 * IN_DIM + lane * 4);
        const uint2 z2 = *(const uint2*)(zb + (size_t)u2 * IN_DIM + lane * 4);
        const uint2 z3 = *(const uint2*)(zb + (size_t)u3 * IN_DIM + lane * 4);

        // two packed words: (edge0, edge1) and (edge2, edge3)
        union { unsigned u; h2v h; } w01, w23;
        w01.h.x = score_head_pk(pa0, fdr, at);
        w01.h.y = score_head_pk(pa1, fdr, at);
        w23.h.x = score_head_pk(pa2, fdr, at);
        w23.h.y = score_head_pk(pa3, fdr, at);
        #pragma unroll
        for (int ofs = 32; ofs > 0; ofs >>= 1) {
            union { int i; h2v h; } t01, t23;
            t01.i = __shfl_xor((int)w01.u, ofs, 64);
            t23.i = __shfl_xor((int)w23.u, ofs, 64);
            w01.h += t01.h;           // v_pk_add_f16
            w23.h += t23.h;
        }
        const float s0 = (float)w01.h.x;
        const float s1 = (float)w01.h.y;
        const float s2 = (float)w23.h.x;
        const float s3 = (float)w23.h.y;
        // scores O(0.2): max-subtraction safely skipped (cancels in num/den
        // anyway, so deferred normalization is exact)
        const float e0 = __expf(s0);
        const float e1 = (e + 1 < deg) ? __expf(s1) : 0.f;
        const float e2 = (e + 2 < deg) ? __expf(s2) : 0.f;
        const float e3 = (e + 3 < deg) ? __expf(s3) : 0.f;
        den += e0 + e1 + e2 + e3;
        const float zc0[4] = {bflo(z0.x), bfhi(z0.x), bflo(z0.y), bfhi(z0.y)};
        const float zc1[4] = {bflo(z1.x), bfhi(z1.x), bflo(z1.y), bfhi(z1.y)};
        const float zc2[4] = {bflo(z2.x), bfhi(z2.x), bflo(z2.y), bfhi(z2.y)};
        const float zc3[4] = {bflo(z3.x), bfhi(z3.x), bflo(z3.y), bfhi(z3.y)};
        #pragma unroll
        for (int c = 0; c < 4; c++)
            acc[c] += (e0 * zc0[c] + e1 * zc1[c]) + (e2 * zc2[c] + e3 * zc3[c]);
    }
    if (deg > 0) {
        const float inv = 1.f / den;
        #pragma unroll
        for (int c = 0; c < 4; c++) acc[c] *= inv;
    }

    union { uint2 u; short s[4]; } pk;
    #pragma unroll
    for (int c = 0; c < 4; c++) {
        const bf16 b = __float2bfloat16(acc[c]);
        pk.s[c] = *(const short*)&b;
    }
    *(uint2*)(agg + (size_t)v * (H_HEADS * IN_DIM) + h * IN_DIM + lane * 4) = pk.u;
}

// ---------------- fallback pair (used only if workspace too small for a
// separate agg buffer; agg then overlays fs, so score/agg must be 2 passes)
__global__ __launch_bounds__(256)
void score_csr_kernel(const f16* __restrict__ fs, const f16* __restrict__ fd,
                      const int* __restrict__ rowptr, const int* __restrict__ csr_src,
                      const f16* __restrict__ atn16, float* __restrict__ expbuf,
                      float* __restrict__ denomB, int N)
{
    const int wave = threadIdx.x >> 6;
    const int lane = threadIdx.x & 63;
    const int wgid = blockIdx.x * 4 + wave;
    const int nw   = gridDim.x * 4;

    uint4 at[H_HEADS];
    #pragma unroll
    for (int h = 0; h < H_HEADS; h++)
        at[h] = *(const uint4*)(atn16 + h * D_HEAD + lane * 8);

    for (int v = wgid; v < N; v += nw) {
        const int off0 = rowptr[v], off1 = rowptr[v + 1];
        if (off0 == off1) continue;
        uint4 fdr[H_HEADS];
        #pragma unroll
        for (int h = 0; h < H_HEADS; h++)
            fdr[h] = *(const uint4*)(fd + (size_t)v * HD + h * D_HEAD + lane * 8);

        float4 den = make_float4(0.f, 0.f, 0.f, 0.f);
        for (int o = off0; o < off1; o += 2) {
            const bool two = (o + 1 < off1);
            const int u0 = csr_src[o];
            const int u1 = two ? csr_src[o + 1] : u0;
            const f16* f0 = fs + (size_t)u0 * HD + lane * 8;
            const f16* f1 = fs + (size_t)u1 * HD + lane * 8;
            uint4 pa0[H_HEADS], pa1[H_HEADS];
            #pragma unroll
            for (int h = 0; h < H_HEADS; h++) pa0[h] = *(const uint4*)(f0 + h * D_HEAD);
            #pragma unroll
            for (int h = 0; h < H_HEADS; h++) pa1[h] = *(const uint4*)(f1 + h * D_HEAD);

            float s0[H_HEADS], s1[H_HEADS];
            #pragma unroll
            for (int h = 0; h < H_HEADS; h++) {
                s0[h] = score_head_h2(pa0[h], fdr[h], at[h]);
                s1[h] = score_head_h2(pa1[h], fdr[h], at[h]);
            }
            #pragma unroll
            for (int ofs = 32; ofs > 0; ofs >>= 1) {
                #pragma unroll
                for (int h = 0; h < H_HEADS; h++) {
                    s0[h] += __shfl_xor(s0[h], ofs, 64);
                    s1[h] += __shfl_xor(s1[h], ofs, 64);
                }
            }
            const float4 e0 = make_float4(expf(s0[0]), expf(s0[1]), expf(s0[2]), expf(s0[3]));
            den.x += e0.x; den.y += e0.y; den.z += e0.z; den.w += e0.w;
            float4 e1;
            if (two) {
                e1 = make_float4(expf(s1[0]), expf(s1[1]), expf(s1[2]), expf(s1[3]));
                den.x += e1.x; den.y += e1.y; den.z += e1.z; den.w += e1.w;
            }
            if (lane == 0) {
                *(float4*)(expbuf + (size_t)o * H_HEADS) = e0;
                if (two) *(float4*)(expbuf + (size_t)(o + 1) * H_HEADS) = e1;
            }
        }
        if (lane == 0) *(float4*)(denomB + (size_t)v * H_HEADS) = den;
    }
}

__global__ __launch_bounds__(256)
void agg_z_kernel(const bf16* __restrict__ zb, const int* __restrict__ rowptr,
                  const int* __restrict__ csr_src, const float* __restrict__ expbuf,
                  const float* __restrict__ denomB, bf16* __restrict__ agg, int N)
{
    const int wave = threadIdx.x >> 6;
    const int lane = threadIdx.x & 63;
    const int wgid = blockIdx.x * 4 + wave;
    const int nw   = gridDim.x * 4;

    for (int v = wgid; v < N; v += nw) {
        const int off0 = rowptr[v], off1 = rowptr[v + 1];
        float acc[H_HEADS][4];
        #pragma unroll
        for (int h = 0; h < H_HEADS; h++)
            #pragma unroll
            for (int c = 0; c < 4; c++) acc[h][c] = 0.f;

        if (off1 > off0) {
            const float4 den = *(const float4*)(denomB + (size_t)v * H_HEADS);
            const float4 inv = make_float4(1.f / den.x, 1.f / den.y, 1.f / den.z, 1.f / den.w);
            int o = off0;
            for (; o + 1 < off1; o += 2) {
                const float4 e0 = *(const float4*)(expbuf + (size_t)o * H_HEADS);
                const float4 e1 = *(const float4*)(expbuf + (size_t)(o + 1) * H_HEADS);
                const int u0 = csr_src[o], u1 = csr_src[o + 1];
                const uint2 z0 = *(const uint2*)(zb + (size_t)u0 * IN_DIM + lane * 4);
                const uint2 z1 = *(const uint2*)(zb + (size_t)u1 * IN_DIM + lane * 4);
                const float a0[4] = {e0.x * inv.x, e0.y * inv.y, e0.z * inv.z, e0.w * inv.w};
                const float a1[4] = {e1.x * inv.x, e1.y * inv.y, e1.z * inv.z, e1.w * inv.w};
                const float zc0[4] = {bflo(z0.x), bfhi(z0.x), bflo(z0.y), bfhi(z0.y)};
                const float zc1[4] = {bflo(z1.x), bfhi(z1.x), bflo(z1.y), bfhi(z1.y)};
                #pragma unroll
                for (int h = 0; h < H_HEADS; h++)
                    #pragma unroll
                    for (int c = 0; c < 4; c++)
                        acc[h][c] += a0[h] * zc0[c] + a1[h] * zc1[c];
            }
            if (o < off1) {
                const float4 e0 = *(const float4*)(expbuf + (size_t)o * H_HEADS);
                const int u0 = csr_src[o];
                const uint2 z0 = *(const uint2*)(zb + (size_t)u0 * IN_DIM + lane * 4);
                const float a0[4] = {e0.x * inv.x, e0.y * inv.y, e0.z * inv.z, e0.w * inv.w};
                const float zc0[4] = {bflo(z0.x), bfhi(z0.x), bflo(z0.y), bfhi(z0.y)};
                #pragma unroll
                for (int h = 0; h < H_HEADS; h++)
                    #pragma unroll
                    for (int c = 0; c < 4; c++)
                        acc[h][c] += a0[h] * zc0[c];
            }
        }
        #pragma unroll
        for (int h = 0; h < H_HEADS; h++) {
            union { uint2 u; short s[4]; } pk;
            #pragma unroll
            for (int c = 0; c < 4; c++) {
                const bf16 b = __float2bfloat16(acc[h][c]);
                pk.s[c] = *(const short*)&b;
            }
            *(uint2*)(agg + (size_t)v * (H_HEADS * IN_DIM) + h * IN_DIM + lane * 4) = pk.u;
        }
    }
}

extern "C" void kernel_launch(void* const* d_in, const int* in_sizes, int n_in,
                              void* d_out, int out_size, void* d_ws, size_t ws_size,
                              hipStream_t stream)
{
    const float* z        = (const float*)d_in[0];
    const int*   src      = (const int*)d_in[1];
    const int*   dst      = (const int*)d_in[2];
    const float* W_src    = (const float*)d_in[3];
    const float* b_src    = (const float*)d_in[4];
    const float* W_dst    = (const float*)d_in[5];
    const float* b_dst    = (const float*)d_in[6];
    const float* attn     = (const float*)d_in[7];
    const float* gat_bias = (const float*)d_in[8];
    const float* W_fc     = (const float*)d_in[9];
    const float* b_fc     = (const float*)d_in[10];
    float* out = (float*)d_out;

    const int N = in_sizes[0] / IN_DIM;   // 20000
    const int E = in_sizes[1];            // 100000
    const int nBlocksScan = (N + 255) / 256;   // 79

    // Workspace (~184 MB base; +41 MB for separate agg if ws_size allows).
    char* p = (char*)d_ws;
    const size_t featB = (size_t)N * HD * 2;
    f16* fs       = (f16*)p;   p += featB;                               // 81.92 MB (f16)
    f16* fd       = (f16*)p;   p += featB;                               // 81.92 MB (f16)
    bf16* zb      = (bf16*)p;  p += (size_t)N * IN_DIM * sizeof(bf16);   // 10.24 MB
    bf16* WsbT    = (bf16*)p;  p += (size_t)HD * IN_DIM * sizeof(bf16);  // 1.05 MB
    bf16* WdbT    = (bf16*)p;  p += (size_t)HD * IN_DIM * sizeof(bf16);  // 1.05 MB
    bf16* Wsb     = (bf16*)p;  p += (size_t)IN_DIM * HD * sizeof(bf16);  // 1.05 MB
    bf16* WfcT    = (bf16*)p;  p += (size_t)HD * D_HEAD * sizeof(bf16);  // 2.10 MB
    bf16* Wfinal  = (bf16*)p;  p += (size_t)OUTD * 1024 * sizeof(bf16);  // 1.05 MB
    float* bias_cat = (float*)p; p += (size_t)2 * HD * sizeof(float);    // 16 KB
    f16* atn16    = (f16*)p;   p += (size_t)HD * sizeof(f16);            // 4 KB
    float* bsW_tot = (float*)p; p += (size_t)OUTD * sizeof(float);
    float* cvec   = (float*)p; p += (size_t)OUTD * sizeof(float);
    float* expbuf = (float*)p; p += (size_t)E * H_HEADS * sizeof(float); // 1.6 MB
    float* denomB = (float*)p; p += (size_t)N * H_HEADS * sizeof(float); // 0.32 MB
    int* cnt      = (int*)p;   p += (size_t)N * 4;                       // N ints
    int* flags    = (int*)p;   p += (size_t)128 * 4;                     // lookback flags
    p = (char*)(((size_t)p + 15) & ~15ULL);
    int* rowptr   = (int*)p;   p += ((size_t)(N + 1) * 4 + 15) & ~15ULL;
    int* cursor   = (int*)p;   p += ((size_t)N * 4 + 15) & ~15ULL;
    int* csr_src  = (int*)p;   p += ((size_t)E * 4 + 15) & ~15ULL;

    // Separate agg buffer (fused score+agg needs fs live while writing agg);
    // fall back to overlaying fs + 2-pass kernels if workspace is too small.
    bf16* aggSep = (bf16*)p;
    const size_t needFused = (size_t)(p - (char*)d_ws) + (size_t)N * (H_HEADS * IN_DIM) * sizeof(bf16);
    const bool fused = (ws_size >= needFused);
    bf16* agg = fused ? aggSep : (bf16*)fs;

    // Prep: tiled transposes + casts + misc (incl. cnt+flags zero) + reductions.
    const int miscElems = 2 * HD + HD + (N + 128);
    const int miscB = (miscElems + 255) / 256;
    prep_kernel<<<2560 + miscB + 2 * OUTD, 256, 0, stream>>>(
        W_src, W_dst, W_fc, b_src, b_dst, attn, b_fc, gat_bias,
        WsbT, WdbT, WfcT, Wsb, bias_cat, atn16, cnt, N + 128, cvec, bsW_tot, miscB);

    // z cast + degree histogram (one launch)
    const long n4 = (long)N * IN_DIM / 4;
    cast_hist_kernel<<<(int)((n4 + E + 255) / 256), 256, 0, stream>>>(z, zb, n4, dst, cnt, E);

    // CSR build: single-pass lookback scan (emits rowptr + cursor), then scatter
    scan_lookback_kernel<<<nBlocksScan, 256, 0, stream>>>(cnt, rowptr, cursor, flags, N);
    scatter_kernel<<<(E + 255) / 256, 256, 0, stream>>>(src, dst, cursor, csr_src, E);

    // FUSED: logical [0,32) = Wfinal GEMM (front -> overlaps), [32,32+nMain) =
    // fs/fd GEMM.
    //   fs,fd = zb @ {W_src,W_dst} + {b_src,b_dst} (f16 out)
    //   Wfinal[j, h*256+k] = Wcomb_h[k, j]         (bf16 out)
    const int gx = HD / 128;                  // 16
    const int gy = (N + 127) / 128;           // 157
    const int nMain = gx * gy * 2;            // 5024
    fused_gemm02_kernel<<<nMain + 32, 256, 0, stream>>>(
        gx, gy, nMain,
        zb, IN_DIM, 0L,
        WsbT, IN_DIM, (long)HD * IN_DIM,
        bias_cat, (long)HD,
        fs, HD, (long)N * HD,
        N, IN_DIM,
        WfcT, D_HEAD, (long)D_HEAD * D_HEAD,
        Wsb, HD, (long)D_HEAD,
        Wfinal, 1024, (long)IN_DIM,
        D_HEAD, D_HEAD);

    // Edge scores + z-space aggregation
    if (fused) {
        score_agg_kernel<<<N, 256, 0, stream>>>(fs, fd, zb, rowptr, csr_src, atn16, agg, N);
    } else {
        score_csr_kernel<<<2500, 256, 0, stream>>>(fs, fd, rowptr, csr_src, atn16, expbuf, denomB, N);
        agg_z_kernel<<<2500, 256, 0, stream>>>(zb, rowptr, csr_src, expbuf, denomB, agg, N);
    }

    // out = lrelu(agg @ Wfinal^T + cvec + deg?bsW_tot), fused epilogue
    mfma_gemm_kernel<1><<<dim3(OUTD / 128, (N + 127) / 128, 1), 256, 0, stream>>>(
        agg, H_HEADS * IN_DIM, 0L,
        Wfinal, H_HEADS * IN_DIM, 0L,
        cvec, 0L, bsW_tot, rowptr,
        out, OUTD, 0L,
        N, H_HEADS * IN_DIM);
}